// Round 3
// baseline (1675.116 us; speedup 1.0000x reference)
//
#include <hip/hip_runtime.h>
#include <math.h>

// ---------------------------------------------------------------------------
// GCN forward, bucketed two-level aggregation (no global CSR, no float atomics
// to HBM).
//   bucket b = dst nodes [b*128, b*128+128)
//   packed[e] = (src << 7) | (dst & 127), stored bucket-contiguous
//   conv: per bucket, accumulate nrm*h[src] into LDS acc[128][32], then
//         out = relu(acc + dinv^2*h + bias)
// ---------------------------------------------------------------------------

#define BN 128           // nodes per bucket
#define BSH 7            // log2(BN)
#define NBUF 1024        // max buckets (N <= 131072)
#define EPB 8192         // edges per scatter block

__global__ void count_kernel(const int* __restrict__ col, int* __restrict__ counts, int E) {
    int e = blockIdx.x * blockDim.x + threadIdx.x;
    if (e < E) atomicAdd(&counts[col[e]], 1);
}

__global__ void dinv_kernel(const int* __restrict__ counts, float* __restrict__ dinv, int N) {
    int i = blockIdx.x * blockDim.x + threadIdx.x;
    if (i < N) dinv[i] = rsqrtf((float)counts[i] + 1.0f);
}

// bucketTotal[b] = sum of counts over the bucket's nodes
__global__ void bucket_sum(const int* __restrict__ counts, int* __restrict__ bt,
                           int N, int NB) {
    int b = blockIdx.x * blockDim.x + threadIdx.x;
    if (b >= NB) return;
    int beg = b << BSH, end = min(beg + BN, N);
    int s = 0;
    for (int i = beg; i < end; ++i) s += counts[i];
    bt[b] = s;
}

// Single-block exclusive scan over NB (<=1024) bucket totals.
// Writes bucketBase[0..NB] (sentinel = E) and inits gCursor.
__global__ void scan_init(const int* __restrict__ bt, int* __restrict__ bucketBase,
                          int* __restrict__ gCursor, int NB, int E) {
    __shared__ int s[NBUF];
    int t = threadIdx.x;
    int v = (t < NB) ? bt[t] : 0;
    s[t] = v;
    __syncthreads();
    for (int off = 1; off < NBUF; off <<= 1) {
        int u = (t >= off) ? s[t - off] : 0;
        __syncthreads();
        s[t] += u;
        __syncthreads();
    }
    if (t < NB) {
        int base = s[t] - v;   // exclusive
        bucketBase[t] = base;
        gCursor[t] = base;
    }
    if (t == 0) bucketBase[NB] = E;
}

// Scatter edges into bucket-contiguous packed array.
// Per-block LDS histogram -> one global cursor atomic per touched bucket ->
// per-edge LDS rank -> write (consecutive slots per (block,bucket)).
__global__ void __launch_bounds__(256)
bucket_scatter(const int* __restrict__ row, const int* __restrict__ col,
               int* __restrict__ gCursor, int* __restrict__ packed, int E, int NB) {
    __shared__ int hist[NBUF];
    __shared__ int base[NBUF];
    int t = threadIdx.x;
    int blockBase = blockIdx.x * EPB;
    for (int i = t; i < NB; i += 256) hist[i] = 0;
    __syncthreads();
    // pass 1: histogram
    for (int i = t; i < EPB; i += 256) {
        int e = blockBase + i;
        if (e < E) atomicAdd(&hist[col[e] >> BSH], 1);
    }
    __syncthreads();
    // grab global ranges, reset hist for rank pass
    for (int b = t; b < NB; b += 256) {
        int c = hist[b];
        base[b] = c ? atomicAdd(&gCursor[b], c) : 0;
        hist[b] = 0;
    }
    __syncthreads();
    // pass 2: rank + write
    for (int i = t; i < EPB; i += 256) {
        int e = blockBase + i;
        if (e < E) {
            int c = col[e];
            int b = c >> BSH;
            int r = atomicAdd(&hist[b], 1);
            packed[base[b] + r] = (row[e] << BSH) | (c & (BN - 1));
        }
    }
}

// out[N,32] = x[N,16] @ W[16,32]
__global__ void gemm_16x32(const float* __restrict__ x, const float* __restrict__ W,
                           float* __restrict__ out, int N) {
    __shared__ float sW[16 * 32];
    __shared__ float sx[8][16];
    int t = threadIdx.x;
    for (int i = t; i < 16 * 32; i += 256) sW[i] = W[i];
    int nodeBase = blockIdx.x * 8;
    if (t < 128) {
        int nn = t >> 4, c = t & 15;
        int g = nodeBase + nn;
        sx[nn][c] = (g < N) ? x[g * 16 + c] : 0.0f;
    }
    __syncthreads();
    int n = t >> 5, k = t & 31;
    int g = nodeBase + n;
    if (g < N) {
        float acc = 0.0f;
#pragma unroll
        for (int c = 0; c < 16; ++c) acc += sx[n][c] * sW[c * 32 + k];
        out[g * 32 + k] = acc;
    }
}

// out[N,32] = hin[N,32] @ W[32,32]
__global__ void gemm_32x32(const float* __restrict__ hin, const float* __restrict__ W,
                           float* __restrict__ out, int N) {
    __shared__ float sW[32 * 32];
    __shared__ float sh[8][32];
    int t = threadIdx.x;
    for (int i = t; i < 32 * 32; i += 256) sW[i] = W[i];
    int nodeBase = blockIdx.x * 8;
    int n = t >> 5, k = t & 31;
    int g = nodeBase + n;
    sh[n][k] = (g < N) ? hin[g * 32 + k] : 0.0f;
    __syncthreads();
    if (g < N) {
        float acc = 0.0f;
#pragma unroll
        for (int c = 0; c < 32; ++c) acc += sh[n][c] * sW[c * 32 + k];
        out[g * 32 + k] = acc;
    }
}

// Per-bucket aggregation into LDS + fused self-loop + bias + ReLU.
// One block per bucket; 8 lanes per edge, float4 channels.
__global__ void __launch_bounds__(256)
bucket_agg(const int* __restrict__ packed, const int* __restrict__ bucketBase,
           const float* __restrict__ dinv, const float* __restrict__ h,
           const float* __restrict__ bias, float* __restrict__ outh, int N) {
    __shared__ float acc[BN][33];   // +1 pad: bank = (dl + c) & 31, spreads dl
    __shared__ float sdinv[BN];
    int bkt = blockIdx.x;
    int t = threadIdx.x;
    int nodeBase = bkt << BSH;
    for (int i = t; i < BN * 33; i += 256) ((float*)acc)[i] = 0.0f;
    if (t < BN) {
        int n = nodeBase + t;
        sdinv[t] = (n < N) ? dinv[n] : 0.0f;
    }
    __syncthreads();
    int beg = bucketBase[bkt], end = bucketBase[bkt + 1];
    int q = t & 7, el = t >> 3;          // 32 edges in flight per iteration
    for (int e = beg + el; e < end; e += 32) {
        int w = packed[e];
        int src = w >> BSH;
        int dl = w & (BN - 1);
        float nrm = dinv[src] * sdinv[dl];
        const float4 hv = *(const float4*)(h + (size_t)src * 32 + q * 4);
        atomicAdd(&acc[dl][q * 4 + 0], nrm * hv.x);
        atomicAdd(&acc[dl][q * 4 + 1], nrm * hv.y);
        atomicAdd(&acc[dl][q * 4 + 2], nrm * hv.z);
        atomicAdd(&acc[dl][q * 4 + 3], nrm * hv.w);
    }
    __syncthreads();
    // epilogue: out = relu(acc + dinv^2*h + bias)
    for (int i = t; i < BN * 8; i += 256) {
        int dl = i >> 3, qq = i & 7;
        int n = nodeBase + dl;
        if (n >= N) continue;
        float di = sdinv[dl];
        float d2 = di * di;
        const float4 hp = *(const float4*)(h + (size_t)n * 32 + qq * 4);
        const float4 bv = *(const float4*)(bias + qq * 4);
        float4 r;
        r.x = fmaxf(acc[dl][qq * 4 + 0] + d2 * hp.x + bv.x, 0.0f);
        r.y = fmaxf(acc[dl][qq * 4 + 1] + d2 * hp.y + bv.y, 0.0f);
        r.z = fmaxf(acc[dl][qq * 4 + 2] + d2 * hp.z + bv.z, 0.0f);
        r.w = fmaxf(acc[dl][qq * 4 + 3] + d2 * hp.w + bv.w, 0.0f);
        *(float4*)(outh + (size_t)n * 32 + qq * 4) = r;
    }
}

// MLP head: h3 = relu(h2@Wl1+bl1); out = h3@Wl4+bl4
__global__ void mlp_head(const float* __restrict__ h2, const float* __restrict__ Wl1,
                         const float* __restrict__ bl1, const float* __restrict__ Wl4,
                         const float* __restrict__ bl4, float* __restrict__ out, int N) {
    __shared__ float sW[32 * 32];
    __shared__ float sh[8][32];
    int t = threadIdx.x;
    for (int i = t; i < 32 * 32; i += 256) sW[i] = Wl1[i];
    int n = t >> 5, k = t & 31;
    int g = blockIdx.x * 8 + n;
    sh[n][k] = (g < N) ? h2[(size_t)g * 32 + k] : 0.0f;
    __syncthreads();
    float h3 = bl1[k];
#pragma unroll
    for (int c = 0; c < 32; ++c) h3 += sh[n][c] * sW[c * 32 + k];
    h3 = fmaxf(h3, 0.0f);
    float p = h3 * Wl4[k];
    p += __shfl_xor(p, 1);
    p += __shfl_xor(p, 2);
    p += __shfl_xor(p, 4);
    p += __shfl_xor(p, 8);
    p += __shfl_xor(p, 16);
    if (g < N && k == 0) out[g] = p + bl4[0];
}

extern "C" void kernel_launch(void* const* d_in, const int* in_sizes, int n_in,
                              void* d_out, int out_size, void* d_ws, size_t ws_size,
                              hipStream_t stream) {
    const float* x   = (const float*)d_in[0];
    const int*   ei  = (const int*)d_in[1];
    const float* W1  = (const float*)d_in[2];
    const float* b1  = (const float*)d_in[3];
    const float* W2  = (const float*)d_in[4];
    const float* b2  = (const float*)d_in[5];
    const float* Wl1 = (const float*)d_in[6];
    const float* bl1 = (const float*)d_in[7];
    const float* Wl4 = (const float*)d_in[8];
    const float* bl4 = (const float*)d_in[9];
    float* out = (float*)d_out;

    const int N = in_sizes[0] / 16;
    const int E = in_sizes[1] / 2;
    const int* row = ei;        // edge_index[0] : source j
    const int* col = ei + E;    // edge_index[1] : target i
    const int NB = (N + BN - 1) >> BSH;

    // workspace layout (512B aligned)
    char* ws = (char*)d_ws;
    auto align = [](size_t v) { return (v + 511) & ~(size_t)511; };
    size_t o = 0;
    int*   counts     = (int*)(ws + o);  o = align(o + (size_t)N * 4);
    int*   bt         = (int*)(ws + o);  o = align(o + (size_t)NBUF * 4);
    int*   bucketBase = (int*)(ws + o);  o = align(o + (size_t)(NBUF + 1) * 4);
    int*   gCursor    = (int*)(ws + o);  o = align(o + (size_t)NBUF * 4);
    float* dinv       = (float*)(ws + o); o = align(o + (size_t)N * 4);
    int*   packed     = (int*)(ws + o);  o = align(o + (size_t)E * 4);
    float* bufA       = (float*)(ws + o); o = align(o + (size_t)N * 32 * 4);
    float* bufB       = (float*)(ws + o); o = align(o + (size_t)N * 32 * 4);

    const int BLK = 256;
    int gridE  = (E + BLK - 1) / BLK;
    int gridN  = (N + BLK - 1) / BLK;
    int gridN8 = (N + 7) / 8;
    int gridSc = (E + EPB - 1) / EPB;
    int gridNB = (NB + BLK - 1) / BLK;

    // --- degrees, bucket layout ---
    hipMemsetAsync(counts, 0, (size_t)N * 4, stream);
    count_kernel<<<gridE, BLK, 0, stream>>>(col, counts, E);
    bucket_sum<<<gridNB, BLK, 0, stream>>>(counts, bt, N, NB);
    scan_init<<<1, NBUF, 0, stream>>>(bt, bucketBase, gCursor, NB, E);
    dinv_kernel<<<gridN, BLK, 0, stream>>>(counts, dinv, N);
    bucket_scatter<<<gridSc, BLK, 0, stream>>>(row, col, gCursor, packed, E, NB);

    // --- conv1 ---
    gemm_16x32<<<gridN8, BLK, 0, stream>>>(x, W1, bufA, N);
    bucket_agg<<<NB, BLK, 0, stream>>>(packed, bucketBase, dinv, bufA, b1, bufB, N);

    // --- conv2 ---
    gemm_32x32<<<gridN8, BLK, 0, stream>>>(bufB, W2, bufA, N);
    bucket_agg<<<NB, BLK, 0, stream>>>(packed, bucketBase, dinv, bufA, b2, bufB, N);

    // --- MLP head ---
    mlp_head<<<gridN8, BLK, 0, stream>>>(bufB, Wl1, bl1, Wl4, bl4, out, N);
}

// Round 4
// 494.395 us; speedup vs baseline: 3.3882x; 3.3882x over previous
//
#include <hip/hip_runtime.h>
#include <math.h>

// ---------------------------------------------------------------------------
// GCN forward. Pipeline:
//   1) counts[i] (int atomics), rowPtr = exscan(counts), dinv = rsqrt(cnt+1)
//   2) bucket_scatter: edges -> packed[(src<<7)|dstLocal], bucket-contiguous
//      (bucket = 128 dst nodes; per-block LDS histogram -> consecutive slots)
//   3) bucket_sort: per bucket, counting-sort into CSR order; emit
//      edges[e] = (src, nrm=dinv[src]*dinv[dst]) as int2. All writes fall in
//      a block-exclusive 32KB window -> full-line writeback, no cross-XCD amp.
//   4) conv = small GEMM + gather_agg (8 lanes/node, massive TLP) fused with
//      self-loop + bias + ReLU.
//   5) fused MLP head.
// ---------------------------------------------------------------------------

#define BN 128           // nodes per bucket
#define BSH 7            // log2(BN)
#define NBUF 1024        // max buckets (N <= 131072)
#define EPB 8192         // edges per scatter block

__global__ void count_kernel(const int* __restrict__ col, int* __restrict__ counts, int E) {
    int e = blockIdx.x * blockDim.x + threadIdx.x;
    if (e < E) atomicAdd(&counts[col[e]], 1);
}

__global__ void dinv_kernel(const int* __restrict__ counts, float* __restrict__ dinv, int N) {
    int i = blockIdx.x * blockDim.x + threadIdx.x;
    if (i < N) dinv[i] = rsqrtf((float)counts[i] + 1.0f);
}

// Per-block inclusive scan (Hillis-Steele) -> exclusive out + block totals.
__global__ void scan_block(const int* __restrict__ counts, int* __restrict__ rowPtr,
                           int* __restrict__ blockSums, int N) {
    __shared__ int s[256];
    int i = blockIdx.x * 256 + threadIdx.x;
    int v = (i < N) ? counts[i] : 0;
    s[threadIdx.x] = v;
    __syncthreads();
    for (int off = 1; off < 256; off <<= 1) {
        int t = (threadIdx.x >= off) ? s[threadIdx.x - off] : 0;
        __syncthreads();
        s[threadIdx.x] += t;
        __syncthreads();
    }
    if (i < N) rowPtr[i] = s[threadIdx.x] - v;          // exclusive
    if (threadIdx.x == 255) blockSums[blockIdx.x] = s[255];
}

// Single-block exclusive scan of block sums (nB <= 512).
__global__ void scan_sums(int* __restrict__ blockSums, int nB) {
    __shared__ int s[512];
    int t = threadIdx.x;
    int v = (t < nB) ? blockSums[t] : 0;
    s[t] = v;
    __syncthreads();
    for (int off = 1; off < 512; off <<= 1) {
        int u = (t >= off) ? s[t - off] : 0;
        __syncthreads();
        s[t] += u;
        __syncthreads();
    }
    if (t < nB) blockSums[t] = s[t] - v;                // exclusive
}

__global__ void add_offsets(int* __restrict__ rowPtr, const int* __restrict__ blockSums,
                            int N, int E) {
    int i = blockIdx.x * blockDim.x + threadIdx.x;
    if (i < N) rowPtr[i] += blockSums[i >> 8];
    if (i == 0) rowPtr[N] = E;
}

// gCursor[b] = rowPtr[b*BN]  (bucket base = CSR offset of its first node)
__global__ void init_gcursor(const int* __restrict__ rowPtr, int* __restrict__ gCursor,
                             int NB) {
    int b = blockIdx.x * blockDim.x + threadIdx.x;
    if (b < NB) gCursor[b] = rowPtr[b << BSH];
}

// Scatter edges into bucket-contiguous packed array.
__global__ void __launch_bounds__(256)
bucket_scatter(const int* __restrict__ row, const int* __restrict__ col,
               int* __restrict__ gCursor, int* __restrict__ packed, int E, int NB) {
    __shared__ int hist[NBUF];
    __shared__ int base[NBUF];
    int t = threadIdx.x;
    int blockBase = blockIdx.x * EPB;
    for (int i = t; i < NB; i += 256) hist[i] = 0;
    __syncthreads();
    for (int i = t; i < EPB; i += 256) {           // pass 1: histogram
        int e = blockBase + i;
        if (e < E) atomicAdd(&hist[col[e] >> BSH], 1);
    }
    __syncthreads();
    for (int b = t; b < NB; b += 256) {            // claim global ranges
        int c = hist[b];
        base[b] = c ? atomicAdd(&gCursor[b], c) : 0;
        hist[b] = 0;
    }
    __syncthreads();
    for (int i = t; i < EPB; i += 256) {           // pass 2: rank + write
        int e = blockBase + i;
        if (e < E) {
            int c = col[e];
            int b = c >> BSH;
            int r = atomicAdd(&hist[b], 1);
            packed[base[b] + r] = (row[e] << BSH) | (c & (BN - 1));
        }
    }
}

// Per-bucket counting sort into CSR order; emit (src, nrm) int2.
__global__ void __launch_bounds__(256)
bucket_sort(const int* __restrict__ packed, const int* __restrict__ rowPtr,
            const float* __restrict__ dinv, int2* __restrict__ edges,
            int N, int E, int NB) {
    __shared__ int cur[BN];
    __shared__ float sdinv[BN];
    int bkt = blockIdx.x;
    int t = threadIdx.x;
    int nodeBase = bkt << BSH;
    if (t < BN) {
        int n = nodeBase + t;
        cur[t] = (n < N) ? rowPtr[n] : E;
        sdinv[t] = (n < N) ? dinv[n] : 0.0f;
    }
    __syncthreads();
    int beg = rowPtr[min(nodeBase, N)];
    int end = (nodeBase + BN <= N) ? rowPtr[nodeBase + BN] : E;
    for (int e = beg + t; e < end; e += 256) {
        int w = packed[e];
        int src = w >> BSH;
        int dl = w & (BN - 1);
        int pos = atomicAdd(&cur[dl], 1);
        int2 ed;
        ed.x = src;
        ed.y = __float_as_int(dinv[src] * sdinv[dl]);
        edges[pos] = ed;
    }
}

// out[N,32] = x[N,16] @ W[16,32]
__global__ void gemm_16x32(const float* __restrict__ x, const float* __restrict__ W,
                           float* __restrict__ out, int N) {
    __shared__ float sW[16 * 32];
    __shared__ float sx[8][16];
    int t = threadIdx.x;
    for (int i = t; i < 16 * 32; i += 256) sW[i] = W[i];
    int nodeBase = blockIdx.x * 8;
    if (t < 128) {
        int nn = t >> 4, c = t & 15;
        int g = nodeBase + nn;
        sx[nn][c] = (g < N) ? x[g * 16 + c] : 0.0f;
    }
    __syncthreads();
    int n = t >> 5, k = t & 31;
    int g = nodeBase + n;
    if (g < N) {
        float acc = 0.0f;
#pragma unroll
        for (int c = 0; c < 16; ++c) acc += sx[n][c] * sW[c * 32 + k];
        out[g * 32 + k] = acc;
    }
}

// out[N,32] = hin[N,32] @ W[32,32]
__global__ void gemm_32x32(const float* __restrict__ hin, const float* __restrict__ W,
                           float* __restrict__ out, int N) {
    __shared__ float sW[32 * 32];
    __shared__ float sh[8][32];
    int t = threadIdx.x;
    for (int i = t; i < 32 * 32; i += 256) sW[i] = W[i];
    int nodeBase = blockIdx.x * 8;
    int n = t >> 5, k = t & 31;
    int g = nodeBase + n;
    sh[n][k] = (g < N) ? hin[g * 32 + k] : 0.0f;
    __syncthreads();
    if (g < N) {
        float acc = 0.0f;
#pragma unroll
        for (int c = 0; c < 32; ++c) acc += sh[n][c] * sW[c * 32 + k];
        out[g * 32 + k] = acc;
    }
}

// Gather-side aggregation, fused with self-loop + bias + ReLU.
// 8 threads per dst node, float4 per thread (32 channels).
__global__ void gather_agg(const int* __restrict__ rowPtr, const int2* __restrict__ edges,
                           const float* __restrict__ h, const float* __restrict__ dinv,
                           const float* __restrict__ b, float* __restrict__ outh, int N) {
    int tt = blockIdx.x * blockDim.x + threadIdx.x;
    int node = tt >> 3;
    if (node >= N) return;
    int q = tt & 7;
    int beg = rowPtr[node], end = rowPtr[node + 1];
    float ax = 0.0f, ay = 0.0f, az = 0.0f, aw = 0.0f;
    for (int e = beg; e < end; ++e) {
        int2 ed = edges[e];
        float w = __int_as_float(ed.y);
        const float4 hv = *(const float4*)(h + (size_t)ed.x * 32 + q * 4);
        ax += w * hv.x; ay += w * hv.y; az += w * hv.z; aw += w * hv.w;
    }
    float di = dinv[node];
    float d2 = di * di;
    const float4 hp = *(const float4*)(h + (size_t)node * 32 + q * 4);
    const float4 bv = *(const float4*)(b + q * 4);
    float4 r;
    r.x = fmaxf(ax + d2 * hp.x + bv.x, 0.0f);
    r.y = fmaxf(ay + d2 * hp.y + bv.y, 0.0f);
    r.z = fmaxf(az + d2 * hp.z + bv.z, 0.0f);
    r.w = fmaxf(aw + d2 * hp.w + bv.w, 0.0f);
    *(float4*)(outh + (size_t)node * 32 + q * 4) = r;
}

// MLP head: h3 = relu(h2@Wl1+bl1); out = h3@Wl4+bl4
__global__ void mlp_head(const float* __restrict__ h2, const float* __restrict__ Wl1,
                         const float* __restrict__ bl1, const float* __restrict__ Wl4,
                         const float* __restrict__ bl4, float* __restrict__ out, int N) {
    __shared__ float sW[32 * 32];
    __shared__ float sh[8][32];
    int t = threadIdx.x;
    for (int i = t; i < 32 * 32; i += 256) sW[i] = Wl1[i];
    int n = t >> 5, k = t & 31;
    int g = blockIdx.x * 8 + n;
    sh[n][k] = (g < N) ? h2[(size_t)g * 32 + k] : 0.0f;
    __syncthreads();
    float h3 = bl1[k];
#pragma unroll
    for (int c = 0; c < 32; ++c) h3 += sh[n][c] * sW[c * 32 + k];
    h3 = fmaxf(h3, 0.0f);
    float p = h3 * Wl4[k];
    p += __shfl_xor(p, 1);
    p += __shfl_xor(p, 2);
    p += __shfl_xor(p, 4);
    p += __shfl_xor(p, 8);
    p += __shfl_xor(p, 16);
    if (g < N && k == 0) out[g] = p + bl4[0];
}

extern "C" void kernel_launch(void* const* d_in, const int* in_sizes, int n_in,
                              void* d_out, int out_size, void* d_ws, size_t ws_size,
                              hipStream_t stream) {
    const float* x   = (const float*)d_in[0];
    const int*   ei  = (const int*)d_in[1];
    const float* W1  = (const float*)d_in[2];
    const float* b1  = (const float*)d_in[3];
    const float* W2  = (const float*)d_in[4];
    const float* b2  = (const float*)d_in[5];
    const float* Wl1 = (const float*)d_in[6];
    const float* bl1 = (const float*)d_in[7];
    const float* Wl4 = (const float*)d_in[8];
    const float* bl4 = (const float*)d_in[9];
    float* out = (float*)d_out;

    const int N = in_sizes[0] / 16;
    const int E = in_sizes[1] / 2;
    const int* row = ei;        // edge_index[0] : source j
    const int* col = ei + E;    // edge_index[1] : target i
    const int NB = (N + BN - 1) >> BSH;

    // workspace layout (512B aligned)
    char* ws = (char*)d_ws;
    auto align = [](size_t v) { return (v + 511) & ~(size_t)511; };
    size_t o = 0;
    int*   counts    = (int*)(ws + o);   o = align(o + (size_t)N * 4);
    int*   rowPtr    = (int*)(ws + o);   o = align(o + (size_t)(N + 1) * 4);
    int*   blockSums = (int*)(ws + o);   o = align(o + 512 * 4);
    int*   gCursor   = (int*)(ws + o);   o = align(o + (size_t)NBUF * 4);
    float* dinv      = (float*)(ws + o); o = align(o + (size_t)N * 4);
    int*   packed    = (int*)(ws + o);   o = align(o + (size_t)E * 4);
    int2*  edges     = (int2*)(ws + o);  o = align(o + (size_t)E * 8);
    float* bufA      = (float*)(ws + o); o = align(o + (size_t)N * 32 * 4);
    float* bufB      = (float*)(ws + o); o = align(o + (size_t)N * 32 * 4);

    const int BLK = 256;
    int gridE  = (E + BLK - 1) / BLK;
    int gridN  = (N + BLK - 1) / BLK;
    int gridN8 = (N + 7) / 8;
    int gridG  = (N * 8 + BLK - 1) / BLK;
    int gridSc = (E + EPB - 1) / EPB;
    int gridNB = (NB + BLK - 1) / BLK;
    int nB     = (N + 255) / 256;

    // --- degrees, CSR layout ---
    hipMemsetAsync(counts, 0, (size_t)N * 4, stream);
    count_kernel<<<gridE, BLK, 0, stream>>>(col, counts, E);
    scan_block<<<nB, 256, 0, stream>>>(counts, rowPtr, blockSums, N);
    scan_sums<<<1, 512, 0, stream>>>(blockSums, nB);
    add_offsets<<<gridN, BLK, 0, stream>>>(rowPtr, blockSums, N, E);
    dinv_kernel<<<gridN, BLK, 0, stream>>>(counts, dinv, N);
    init_gcursor<<<gridNB, BLK, 0, stream>>>(rowPtr, gCursor, NB);

    // --- edge reorder: bucket pass, then per-bucket counting sort ---
    bucket_scatter<<<gridSc, BLK, 0, stream>>>(row, col, gCursor, packed, E, NB);
    bucket_sort<<<NB, BLK, 0, stream>>>(packed, rowPtr, dinv, edges, N, E, NB);

    // --- conv1 ---
    gemm_16x32<<<gridN8, BLK, 0, stream>>>(x, W1, bufA, N);
    gather_agg<<<gridG, BLK, 0, stream>>>(rowPtr, edges, bufA, dinv, b1, bufB, N);

    // --- conv2 ---
    gemm_32x32<<<gridN8, BLK, 0, stream>>>(bufB, W2, bufA, N);
    gather_agg<<<gridG, BLK, 0, stream>>>(rowPtr, edges, bufA, dinv, b2, bufB, N);

    // --- MLP head ---
    mlp_head<<<gridN8, BLK, 0, stream>>>(bufB, Wl1, bl1, Wl4, bl4, out, N);
}

// Round 5
// 382.750 us; speedup vs baseline: 4.3765x; 1.2917x over previous
//
#include <hip/hip_runtime.h>
#include <math.h>

// ---------------------------------------------------------------------------
// GCN forward. Pipeline (no per-node global atomics anywhere):
//   1) bucket_hist: per-block LDS hist over buckets -> bt[] (≈300k atomics on
//      3KB, vs 3.2M on 400KB for per-node counts)
//   2) scan_init: exscan(bt) -> bucketBase[0..NB], gCursor
//   3) bucket_scatter: edges -> packed[(src<<7)|dstLocal], bucket-contiguous
//   4) bucket_stats: per bucket, LDS hist of dst-locals -> rowPtr + dinv
//      (in-block scan; zero global atomics)
//   5) bucket_sort: per bucket counting-sort -> edges[e]=(src,nrm) int2 in CSR
//      order; writes land in block-exclusive windows (full-line writeback)
//   6) conv = small GEMM + gather_agg (8 lanes/node) fused self-loop+bias+ReLU
//   7) fused MLP head
// ---------------------------------------------------------------------------

#define BN 128           // nodes per bucket
#define BSH 7            // log2(BN)
#define NBUF 1024        // max buckets (N <= 131072)
#define EPB 8192         // edges per scatter block

// Per-block LDS histogram over buckets, flush to global bt[].
__global__ void __launch_bounds__(256)
bucket_hist(const int* __restrict__ col, int* __restrict__ bt, int E, int NB) {
    __shared__ int hist[NBUF];
    int t = threadIdx.x;
    int blockBase = blockIdx.x * EPB;
    for (int i = t; i < NB; i += 256) hist[i] = 0;
    __syncthreads();
    for (int i = t; i < EPB; i += 256) {
        int e = blockBase + i;
        if (e < E) atomicAdd(&hist[col[e] >> BSH], 1);
    }
    __syncthreads();
    for (int b = t; b < NB; b += 256) {
        int c = hist[b];
        if (c) atomicAdd(&bt[b], c);
    }
}

// Single-block exclusive scan over NB (<=1024) bucket totals.
// Writes bucketBase[0..NB] (sentinel = E) and inits gCursor.
__global__ void scan_init(const int* __restrict__ bt, int* __restrict__ bucketBase,
                          int* __restrict__ gCursor, int NB, int E) {
    __shared__ int s[NBUF];
    int t = threadIdx.x;
    int v = (t < NB) ? bt[t] : 0;
    s[t] = v;
    __syncthreads();
    for (int off = 1; off < NBUF; off <<= 1) {
        int u = (t >= off) ? s[t - off] : 0;
        __syncthreads();
        s[t] += u;
        __syncthreads();
    }
    if (t < NB) {
        int base = s[t] - v;   // exclusive
        bucketBase[t] = base;
        gCursor[t] = base;
    }
    if (t == 0) bucketBase[NB] = E;
}

// Scatter edges into bucket-contiguous packed array.
__global__ void __launch_bounds__(256)
bucket_scatter(const int* __restrict__ row, const int* __restrict__ col,
               int* __restrict__ gCursor, int* __restrict__ packed, int E, int NB) {
    __shared__ int hist[NBUF];
    __shared__ int base[NBUF];
    int t = threadIdx.x;
    int blockBase = blockIdx.x * EPB;
    for (int i = t; i < NB; i += 256) hist[i] = 0;
    __syncthreads();
    for (int i = t; i < EPB; i += 256) {           // pass 1: histogram
        int e = blockBase + i;
        if (e < E) atomicAdd(&hist[col[e] >> BSH], 1);
    }
    __syncthreads();
    for (int b = t; b < NB; b += 256) {            // claim global ranges
        int c = hist[b];
        base[b] = c ? atomicAdd(&gCursor[b], c) : 0;
        hist[b] = 0;
    }
    __syncthreads();
    for (int i = t; i < EPB; i += 256) {           // pass 2: rank + write
        int e = blockBase + i;
        if (e < E) {
            int c = col[e];
            int b = c >> BSH;
            int r = atomicAdd(&hist[b], 1);
            packed[base[b] + r] = (row[e] << BSH) | (c & (BN - 1));
        }
    }
}

// Per bucket: degree histogram (LDS) -> rowPtr (in-block exscan) + dinv.
__global__ void __launch_bounds__(256)
bucket_stats(const int* __restrict__ packed, const int* __restrict__ bucketBase,
             int* __restrict__ rowPtr, float* __restrict__ dinv, int N, int E, int NB) {
    __shared__ int cnt[BN];
    __shared__ int sc[BN];
    int bkt = blockIdx.x;
    int t = threadIdx.x;
    int nodeBase = bkt << BSH;
    if (t < BN) cnt[t] = 0;
    __syncthreads();
    int beg = bucketBase[bkt], end = bucketBase[bkt + 1];
    for (int e = beg + t; e < end; e += 256)
        atomicAdd(&cnt[packed[e] & (BN - 1)], 1);
    __syncthreads();
    if (t < BN) sc[t] = cnt[t];
    __syncthreads();
    for (int off = 1; off < BN; off <<= 1) {
        int v = (t < BN && t >= off) ? sc[t - off] : 0;
        __syncthreads();
        if (t < BN) sc[t] += v;
        __syncthreads();
    }
    if (t < BN) {
        int n = nodeBase + t;
        if (n < N) {
            rowPtr[n] = beg + sc[t] - cnt[t];            // exclusive
            dinv[n] = rsqrtf((float)cnt[t] + 1.0f);      // +1 self loop
        }
    }
    if (bkt == NB - 1 && t == 0) rowPtr[N] = E;
}

// Per-bucket counting sort into CSR order; emit (src, nrm) int2.
__global__ void __launch_bounds__(256)
bucket_sort(const int* __restrict__ packed, const int* __restrict__ rowPtr,
            const float* __restrict__ dinv, int2* __restrict__ edges,
            int N, int E, int NB) {
    __shared__ int cur[BN];
    __shared__ float sdinv[BN];
    int bkt = blockIdx.x;
    int t = threadIdx.x;
    int nodeBase = bkt << BSH;
    if (t < BN) {
        int n = nodeBase + t;
        cur[t] = (n < N) ? rowPtr[n] : E;
        sdinv[t] = (n < N) ? dinv[n] : 0.0f;
    }
    __syncthreads();
    int beg = rowPtr[min(nodeBase, N)];
    int end = (nodeBase + BN <= N) ? rowPtr[nodeBase + BN] : E;
    for (int e = beg + t; e < end; e += 256) {
        int w = packed[e];
        int src = w >> BSH;
        int dl = w & (BN - 1);
        int pos = atomicAdd(&cur[dl], 1);
        int2 ed;
        ed.x = src;
        ed.y = __float_as_int(dinv[src] * sdinv[dl]);
        edges[pos] = ed;
    }
}

// out[N,32] = x[N,16] @ W[16,32]
__global__ void gemm_16x32(const float* __restrict__ x, const float* __restrict__ W,
                           float* __restrict__ out, int N) {
    __shared__ float sW[16 * 32];
    __shared__ float sx[8][16];
    int t = threadIdx.x;
    for (int i = t; i < 16 * 32; i += 256) sW[i] = W[i];
    int nodeBase = blockIdx.x * 8;
    if (t < 128) {
        int nn = t >> 4, c = t & 15;
        int g = nodeBase + nn;
        sx[nn][c] = (g < N) ? x[g * 16 + c] : 0.0f;
    }
    __syncthreads();
    int n = t >> 5, k = t & 31;
    int g = nodeBase + n;
    if (g < N) {
        float acc = 0.0f;
#pragma unroll
        for (int c = 0; c < 16; ++c) acc += sx[n][c] * sW[c * 32 + k];
        out[g * 32 + k] = acc;
    }
}

// out[N,32] = hin[N,32] @ W[32,32]
__global__ void gemm_32x32(const float* __restrict__ hin, const float* __restrict__ W,
                           float* __restrict__ out, int N) {
    __shared__ float sW[32 * 32];
    __shared__ float sh[8][32];
    int t = threadIdx.x;
    for (int i = t; i < 32 * 32; i += 256) sW[i] = W[i];
    int nodeBase = blockIdx.x * 8;
    int n = t >> 5, k = t & 31;
    int g = nodeBase + n;
    sh[n][k] = (g < N) ? hin[g * 32 + k] : 0.0f;
    __syncthreads();
    if (g < N) {
        float acc = 0.0f;
#pragma unroll
        for (int c = 0; c < 32; ++c) acc += sh[n][c] * sW[c * 32 + k];
        out[g * 32 + k] = acc;
    }
}

// Gather-side aggregation, fused with self-loop + bias + ReLU.
// 8 threads per dst node, float4 per thread (32 channels).
__global__ void gather_agg(const int* __restrict__ rowPtr, const int2* __restrict__ edges,
                           const float* __restrict__ h, const float* __restrict__ dinv,
                           const float* __restrict__ b, float* __restrict__ outh, int N) {
    int tt = blockIdx.x * blockDim.x + threadIdx.x;
    int node = tt >> 3;
    if (node >= N) return;
    int q = tt & 7;
    int beg = rowPtr[node], end = rowPtr[node + 1];
    float ax = 0.0f, ay = 0.0f, az = 0.0f, aw = 0.0f;
    for (int e = beg; e < end; ++e) {
        int2 ed = edges[e];
        float w = __int_as_float(ed.y);
        const float4 hv = *(const float4*)(h + (size_t)ed.x * 32 + q * 4);
        ax += w * hv.x; ay += w * hv.y; az += w * hv.z; aw += w * hv.w;
    }
    float di = dinv[node];
    float d2 = di * di;
    const float4 hp = *(const float4*)(h + (size_t)node * 32 + q * 4);
    const float4 bv = *(const float4*)(b + q * 4);
    float4 r;
    r.x = fmaxf(ax + d2 * hp.x + bv.x, 0.0f);
    r.y = fmaxf(ay + d2 * hp.y + bv.y, 0.0f);
    r.z = fmaxf(az + d2 * hp.z + bv.z, 0.0f);
    r.w = fmaxf(aw + d2 * hp.w + bv.w, 0.0f);
    *(float4*)(outh + (size_t)node * 32 + q * 4) = r;
}

// MLP head: h3 = relu(h2@Wl1+bl1); out = h3@Wl4+bl4
__global__ void mlp_head(const float* __restrict__ h2, const float* __restrict__ Wl1,
                         const float* __restrict__ bl1, const float* __restrict__ Wl4,
                         const float* __restrict__ bl4, float* __restrict__ out, int N) {
    __shared__ float sW[32 * 32];
    __shared__ float sh[8][32];
    int t = threadIdx.x;
    for (int i = t; i < 32 * 32; i += 256) sW[i] = Wl1[i];
    int n = t >> 5, k = t & 31;
    int g = blockIdx.x * 8 + n;
    sh[n][k] = (g < N) ? h2[(size_t)g * 32 + k] : 0.0f;
    __syncthreads();
    float h3 = bl1[k];
#pragma unroll
    for (int c = 0; c < 32; ++c) h3 += sh[n][c] * sW[c * 32 + k];
    h3 = fmaxf(h3, 0.0f);
    float p = h3 * Wl4[k];
    p += __shfl_xor(p, 1);
    p += __shfl_xor(p, 2);
    p += __shfl_xor(p, 4);
    p += __shfl_xor(p, 8);
    p += __shfl_xor(p, 16);
    if (g < N && k == 0) out[g] = p + bl4[0];
}

extern "C" void kernel_launch(void* const* d_in, const int* in_sizes, int n_in,
                              void* d_out, int out_size, void* d_ws, size_t ws_size,
                              hipStream_t stream) {
    const float* x   = (const float*)d_in[0];
    const int*   ei  = (const int*)d_in[1];
    const float* W1  = (const float*)d_in[2];
    const float* b1  = (const float*)d_in[3];
    const float* W2  = (const float*)d_in[4];
    const float* b2  = (const float*)d_in[5];
    const float* Wl1 = (const float*)d_in[6];
    const float* bl1 = (const float*)d_in[7];
    const float* Wl4 = (const float*)d_in[8];
    const float* bl4 = (const float*)d_in[9];
    float* out = (float*)d_out;

    const int N = in_sizes[0] / 16;
    const int E = in_sizes[1] / 2;
    const int* row = ei;        // edge_index[0] : source j
    const int* col = ei + E;    // edge_index[1] : target i
    const int NB = (N + BN - 1) >> BSH;

    // workspace layout (512B aligned)
    char* ws = (char*)d_ws;
    auto align = [](size_t v) { return (v + 511) & ~(size_t)511; };
    size_t o = 0;
    int*   bt         = (int*)(ws + o);   o = align(o + (size_t)NBUF * 4);
    int*   bucketBase = (int*)(ws + o);   o = align(o + (size_t)(NBUF + 1) * 4);
    int*   gCursor    = (int*)(ws + o);   o = align(o + (size_t)NBUF * 4);
    int*   rowPtr     = (int*)(ws + o);   o = align(o + (size_t)(N + 1) * 4);
    float* dinv       = (float*)(ws + o); o = align(o + (size_t)N * 4);
    int*   packed     = (int*)(ws + o);   o = align(o + (size_t)E * 4);
    int2*  edges      = (int2*)(ws + o);  o = align(o + (size_t)E * 8);
    float* bufA       = (float*)(ws + o); o = align(o + (size_t)N * 32 * 4);
    float* bufB       = (float*)(ws + o); o = align(o + (size_t)N * 32 * 4);

    const int BLK = 256;
    int gridN8 = (N + 7) / 8;
    int gridG  = (N * 8 + BLK - 1) / BLK;
    int gridSc = (E + EPB - 1) / EPB;

    // --- bucket layout + edge reorder ---
    hipMemsetAsync(bt, 0, (size_t)NBUF * 4, stream);
    bucket_hist<<<gridSc, BLK, 0, stream>>>(col, bt, E, NB);
    scan_init<<<1, NBUF, 0, stream>>>(bt, bucketBase, gCursor, NB, E);
    bucket_scatter<<<gridSc, BLK, 0, stream>>>(row, col, gCursor, packed, E, NB);
    bucket_stats<<<NB, BLK, 0, stream>>>(packed, bucketBase, rowPtr, dinv, N, E, NB);
    bucket_sort<<<NB, BLK, 0, stream>>>(packed, rowPtr, dinv, edges, N, E, NB);

    // --- conv1 ---
    gemm_16x32<<<gridN8, BLK, 0, stream>>>(x, W1, bufA, N);
    gather_agg<<<gridG, BLK, 0, stream>>>(rowPtr, edges, bufA, dinv, b1, bufB, N);

    // --- conv2 ---
    gemm_32x32<<<gridN8, BLK, 0, stream>>>(bufB, W2, bufA, N);
    gather_agg<<<gridG, BLK, 0, stream>>>(rowPtr, edges, bufA, dinv, b2, bufB, N);

    // --- MLP head ---
    mlp_head<<<gridN8, BLK, 0, stream>>>(bufB, Wl1, bl1, Wl4, bl4, out, N);
}

// Round 6
// 377.776 us; speedup vs baseline: 4.4342x; 1.0132x over previous
//
#include <hip/hip_runtime.h>
#include <math.h>

// ---------------------------------------------------------------------------
// GCN forward. Pipeline (no per-node global atomics):
//   1) bucket_hist: per-block LDS hist over 196 buckets -> bt[]
//   2) scan_init: exscan(bt) -> bucketBase, gCursor
//   3) bucket_scatter: edges -> packed[(src<<9)|dstLocal], bucket-contiguous
//      (BN=512 -> 42-edge runs per (block,bucket) -> ~full-line writes)
//   4) bucket_finalize: per bucket, LDS degree hist -> rowPtr + dinv, then
//      counting-sort -> srcs[e] (src only; 4B/edge) in CSR order
//   5) conv: small GEMM + gather_agg. Norm factorizes:
//      out[i] = relu(dinv[i]*sum_e dinv[src]*h[src] + dinv[i]^2*h[i] + b)
//   6) fused MLP head
// ---------------------------------------------------------------------------

#define BN 512           // nodes per bucket
#define BSH 9            // log2(BN)
#define NBUF 256         // max buckets (N <= 131072)
#define EPB 8192         // edges per scatter block

// Per-block LDS histogram over buckets, flush to global bt[].
__global__ void __launch_bounds__(256)
bucket_hist(const int* __restrict__ col, int* __restrict__ bt, int E, int NB) {
    __shared__ int hist[NBUF];
    int t = threadIdx.x;
    int blockBase = blockIdx.x * EPB;
    for (int i = t; i < NB; i += 256) hist[i] = 0;
    __syncthreads();
    for (int i = t; i < EPB; i += 256) {
        int e = blockBase + i;
        if (e < E) atomicAdd(&hist[col[e] >> BSH], 1);
    }
    __syncthreads();
    for (int b = t; b < NB; b += 256) {
        int c = hist[b];
        if (c) atomicAdd(&bt[b], c);
    }
}

// Single-block exclusive scan over NB (<=256) bucket totals.
__global__ void scan_init(const int* __restrict__ bt, int* __restrict__ bucketBase,
                          int* __restrict__ gCursor, int NB, int E) {
    __shared__ int s[NBUF];
    int t = threadIdx.x;
    int v = (t < NB) ? bt[t] : 0;
    s[t] = v;
    __syncthreads();
    for (int off = 1; off < NBUF; off <<= 1) {
        int u = (t >= off) ? s[t - off] : 0;
        __syncthreads();
        s[t] += u;
        __syncthreads();
    }
    if (t < NB) {
        int base = s[t] - v;   // exclusive
        bucketBase[t] = base;
        gCursor[t] = base;
    }
    if (t == 0) bucketBase[NB] = E;
}

// Scatter edges into bucket-contiguous packed array.
__global__ void __launch_bounds__(256)
bucket_scatter(const int* __restrict__ row, const int* __restrict__ col,
               int* __restrict__ gCursor, int* __restrict__ packed, int E, int NB) {
    __shared__ int hist[NBUF];
    __shared__ int base[NBUF];
    int t = threadIdx.x;
    int blockBase = blockIdx.x * EPB;
    for (int i = t; i < NB; i += 256) hist[i] = 0;
    __syncthreads();
    for (int i = t; i < EPB; i += 256) {           // pass 1: histogram
        int e = blockBase + i;
        if (e < E) atomicAdd(&hist[col[e] >> BSH], 1);
    }
    __syncthreads();
    for (int b = t; b < NB; b += 256) {            // claim global ranges
        int c = hist[b];
        base[b] = c ? atomicAdd(&gCursor[b], c) : 0;
        hist[b] = 0;
    }
    __syncthreads();
    for (int i = t; i < EPB; i += 256) {           // pass 2: rank + write
        int e = blockBase + i;
        if (e < E) {
            int c = col[e];
            int b = c >> BSH;
            int r = atomicAdd(&hist[b], 1);
            packed[base[b] + r] = (row[e] << BSH) | (c & (BN - 1));
        }
    }
}

// Per bucket: degree hist -> rowPtr + dinv (in-block exscan over 512 via
// pair-scan with 256 threads), then counting-sort emitting srcs[] only.
__global__ void __launch_bounds__(256)
bucket_finalize(const int* __restrict__ packed, const int* __restrict__ bucketBase,
                int* __restrict__ rowPtr, float* __restrict__ dinv,
                int* __restrict__ srcs, int N, int E) {
    __shared__ int cnt[BN];
    __shared__ int ps[256];
    __shared__ int cur[BN];
    int bkt = blockIdx.x;
    int t = threadIdx.x;
    int nodeBase = bkt << BSH;
    cnt[t] = 0;
    cnt[t + 256] = 0;
    __syncthreads();
    int beg = bucketBase[bkt], end = bucketBase[bkt + 1];
    for (int e = beg + t; e < end; e += 256)
        atomicAdd(&cnt[packed[e] & (BN - 1)], 1);
    __syncthreads();
    int v0 = cnt[2 * t], v1 = cnt[2 * t + 1];
    int s = v0 + v1;
    ps[t] = s;
    __syncthreads();
    for (int off = 1; off < 256; off <<= 1) {      // inclusive scan of pair sums
        int u = (t >= off) ? ps[t - off] : 0;
        __syncthreads();
        ps[t] += u;
        __syncthreads();
    }
    int p0 = beg + ps[t] - s;                      // exclusive prefix
    int p1 = p0 + v0;
    cur[2 * t] = p0;
    cur[2 * t + 1] = p1;
    int n0 = nodeBase + 2 * t, n1 = n0 + 1;
    if (n0 < N) { rowPtr[n0] = p0; dinv[n0] = rsqrtf((float)v0 + 1.0f); }
    if (n1 < N) { rowPtr[n1] = p1; dinv[n1] = rsqrtf((float)v1 + 1.0f); }
    if (bkt == 0 && t == 0) rowPtr[N] = E;
    __syncthreads();
    for (int e = beg + t; e < end; e += 256) {     // counting sort (2nd read: L2)
        int w = packed[e];
        int pos = atomicAdd(&cur[w & (BN - 1)], 1);
        srcs[pos] = w >> BSH;
    }
}

// out[N,32] = x[N,16] @ W[16,32]
__global__ void gemm_16x32(const float* __restrict__ x, const float* __restrict__ W,
                           float* __restrict__ out, int N) {
    __shared__ float sW[16 * 32];
    __shared__ float sx[8][16];
    int t = threadIdx.x;
    for (int i = t; i < 16 * 32; i += 256) sW[i] = W[i];
    int nodeBase = blockIdx.x * 8;
    if (t < 128) {
        int nn = t >> 4, c = t & 15;
        int g = nodeBase + nn;
        sx[nn][c] = (g < N) ? x[g * 16 + c] : 0.0f;
    }
    __syncthreads();
    int n = t >> 5, k = t & 31;
    int g = nodeBase + n;
    if (g < N) {
        float acc = 0.0f;
#pragma unroll
        for (int c = 0; c < 16; ++c) acc += sx[n][c] * sW[c * 32 + k];
        out[g * 32 + k] = acc;
    }
}

// out[N,32] = hin[N,32] @ W[32,32]
__global__ void gemm_32x32(const float* __restrict__ hin, const float* __restrict__ W,
                           float* __restrict__ out, int N) {
    __shared__ float sW[32 * 32];
    __shared__ float sh[8][32];
    int t = threadIdx.x;
    for (int i = t; i < 32 * 32; i += 256) sW[i] = W[i];
    int nodeBase = blockIdx.x * 8;
    int n = t >> 5, k = t & 31;
    int g = nodeBase + n;
    sh[n][k] = (g < N) ? hin[g * 32 + k] : 0.0f;
    __syncthreads();
    if (g < N) {
        float acc = 0.0f;
#pragma unroll
        for (int c = 0; c < 32; ++c) acc += sh[n][c] * sW[c * 32 + k];
        out[g * 32 + k] = acc;
    }
}

// Gather-side aggregation. 8 threads per dst node, float4 per thread.
// out[i] = relu(di * sum_e dinv[src]*h[src] + di^2*h[i] + b)
__global__ void gather_agg(const int* __restrict__ rowPtr, const int* __restrict__ srcs,
                           const float* __restrict__ h, const float* __restrict__ dinv,
                           const float* __restrict__ b, float* __restrict__ outh, int N) {
    int tt = blockIdx.x * blockDim.x + threadIdx.x;
    int node = tt >> 3;
    if (node >= N) return;
    int q = tt & 7;
    int beg = rowPtr[node], end = rowPtr[node + 1];
    float ax = 0.0f, ay = 0.0f, az = 0.0f, aw = 0.0f;
    for (int e = beg; e < end; ++e) {
        int s = srcs[e];
        float ws = dinv[s];
        const float4 hv = *(const float4*)(h + (size_t)s * 32 + q * 4);
        ax += ws * hv.x; ay += ws * hv.y; az += ws * hv.z; aw += ws * hv.w;
    }
    float di = dinv[node];
    float d2 = di * di;
    const float4 hp = *(const float4*)(h + (size_t)node * 32 + q * 4);
    const float4 bv = *(const float4*)(b + q * 4);
    float4 r;
    r.x = fmaxf(di * ax + d2 * hp.x + bv.x, 0.0f);
    r.y = fmaxf(di * ay + d2 * hp.y + bv.y, 0.0f);
    r.z = fmaxf(di * az + d2 * hp.z + bv.z, 0.0f);
    r.w = fmaxf(di * aw + d2 * hp.w + bv.w, 0.0f);
    *(float4*)(outh + (size_t)node * 32 + q * 4) = r;
}

// MLP head: h3 = relu(h2@Wl1+bl1); out = h3@Wl4+bl4
__global__ void mlp_head(const float* __restrict__ h2, const float* __restrict__ Wl1,
                         const float* __restrict__ bl1, const float* __restrict__ Wl4,
                         const float* __restrict__ bl4, float* __restrict__ out, int N) {
    __shared__ float sW[32 * 32];
    __shared__ float sh[8][32];
    int t = threadIdx.x;
    for (int i = t; i < 32 * 32; i += 256) sW[i] = Wl1[i];
    int n = t >> 5, k = t & 31;
    int g = blockIdx.x * 8 + n;
    sh[n][k] = (g < N) ? h2[(size_t)g * 32 + k] : 0.0f;
    __syncthreads();
    float h3 = bl1[k];
#pragma unroll
    for (int c = 0; c < 32; ++c) h3 += sh[n][c] * sW[c * 32 + k];
    h3 = fmaxf(h3, 0.0f);
    float p = h3 * Wl4[k];
    p += __shfl_xor(p, 1);
    p += __shfl_xor(p, 2);
    p += __shfl_xor(p, 4);
    p += __shfl_xor(p, 8);
    p += __shfl_xor(p, 16);
    if (g < N && k == 0) out[g] = p + bl4[0];
}

extern "C" void kernel_launch(void* const* d_in, const int* in_sizes, int n_in,
                              void* d_out, int out_size, void* d_ws, size_t ws_size,
                              hipStream_t stream) {
    const float* x   = (const float*)d_in[0];
    const int*   ei  = (const int*)d_in[1];
    const float* W1  = (const float*)d_in[2];
    const float* b1  = (const float*)d_in[3];
    const float* W2  = (const float*)d_in[4];
    const float* b2  = (const float*)d_in[5];
    const float* Wl1 = (const float*)d_in[6];
    const float* bl1 = (const float*)d_in[7];
    const float* Wl4 = (const float*)d_in[8];
    const float* bl4 = (const float*)d_in[9];
    float* out = (float*)d_out;

    const int N = in_sizes[0] / 16;
    const int E = in_sizes[1] / 2;
    const int* row = ei;        // edge_index[0] : source j
    const int* col = ei + E;    // edge_index[1] : target i
    const int NB = (N + BN - 1) >> BSH;

    // workspace layout (512B aligned)
    char* ws = (char*)d_ws;
    auto align = [](size_t v) { return (v + 511) & ~(size_t)511; };
    size_t o = 0;
    int*   bt         = (int*)(ws + o);   o = align(o + (size_t)NBUF * 4);
    int*   bucketBase = (int*)(ws + o);   o = align(o + (size_t)(NBUF + 1) * 4);
    int*   gCursor    = (int*)(ws + o);   o = align(o + (size_t)NBUF * 4);
    int*   rowPtr     = (int*)(ws + o);   o = align(o + (size_t)(N + 1) * 4);
    float* dinv       = (float*)(ws + o); o = align(o + (size_t)N * 4);
    int*   packed     = (int*)(ws + o);   o = align(o + (size_t)E * 4);
    int*   srcs       = (int*)(ws + o);   o = align(o + (size_t)E * 4);
    float* bufA       = (float*)(ws + o); o = align(o + (size_t)N * 32 * 4);
    float* bufB       = (float*)(ws + o); o = align(o + (size_t)N * 32 * 4);

    const int BLK = 256;
    int gridN8 = (N + 7) / 8;
    int gridG  = (N * 8 + BLK - 1) / BLK;
    int gridSc = (E + EPB - 1) / EPB;

    // --- bucket layout + edge reorder ---
    hipMemsetAsync(bt, 0, (size_t)NBUF * 4, stream);
    bucket_hist<<<gridSc, BLK, 0, stream>>>(col, bt, E, NB);
    scan_init<<<1, NBUF, 0, stream>>>(bt, bucketBase, gCursor, NB, E);
    bucket_scatter<<<gridSc, BLK, 0, stream>>>(row, col, gCursor, packed, E, NB);
    bucket_finalize<<<NB, BLK, 0, stream>>>(packed, bucketBase, rowPtr, dinv, srcs, N, E);

    // --- conv1 ---
    gemm_16x32<<<gridN8, BLK, 0, stream>>>(x, W1, bufA, N);
    gather_agg<<<gridG, BLK, 0, stream>>>(rowPtr, srcs, bufA, dinv, b1, bufB, N);

    // --- conv2 ---
    gemm_32x32<<<gridN8, BLK, 0, stream>>>(bufB, W2, bufA, N);
    gather_agg<<<gridG, BLK, 0, stream>>>(rowPtr, srcs, bufA, dinv, b2, bufB, N);

    // --- MLP head ---
    mlp_head<<<gridN8, BLK, 0, stream>>>(bufB, Wl1, bl1, Wl4, bl4, out, N);
}

// Round 7
// 319.244 us; speedup vs baseline: 5.2471x; 1.1833x over previous
//
#include <hip/hip_runtime.h>
#include <math.h>

// ---------------------------------------------------------------------------
// GCN forward, fully fused. Using linearity: A(XW) = (AX)W, and factorized
// norm with prescaled features:
//   xs = dinv .* x
//   A1[i] = dinv[i]*(sum_{e:dst=i} xs[src] + xs[i]);  h1 = relu(A1@W1+b1)
//   hs1 = dinv .* h1
//   A2[i] = dinv[i]*(sum_e hs1[src] + hs1[i]);        h2 = relu(A2@W2+b2)
//   out  = relu(h2@Wl1+bl1) @ Wl4 + bl4
// Pipeline: bucket_hist -> scan_init -> bucket_scatter (dst-bucket reorder)
//   -> bucket_finalize (rowPtr+dinv+counting sort -> srcs; prescale xs)
//   -> gather_conv1 (gather xs, fused W1 GEMM) -> gather_conv2_head
// ---------------------------------------------------------------------------

#define BN 512           // nodes per bucket
#define BSH 9            // log2(BN)
#define NBUF 256         // max buckets (N <= 131072)
#define EPB 8192         // edges per scatter block

// Per-block LDS histogram over buckets, flush to global bt[].
__global__ void __launch_bounds__(256)
bucket_hist(const int* __restrict__ col, int* __restrict__ bt, int E, int NB) {
    __shared__ int hist[NBUF];
    int t = threadIdx.x;
    int blockBase = blockIdx.x * EPB;
    for (int i = t; i < NB; i += 256) hist[i] = 0;
    __syncthreads();
    for (int i = t; i < EPB; i += 256) {
        int e = blockBase + i;
        if (e < E) atomicAdd(&hist[col[e] >> BSH], 1);
    }
    __syncthreads();
    for (int b = t; b < NB; b += 256) {
        int c = hist[b];
        if (c) atomicAdd(&bt[b], c);
    }
}

// Single-block exclusive scan over NB (<=256) bucket totals.
__global__ void scan_init(const int* __restrict__ bt, int* __restrict__ bucketBase,
                          int* __restrict__ gCursor, int NB, int E) {
    __shared__ int s[NBUF];
    int t = threadIdx.x;
    int v = (t < NB) ? bt[t] : 0;
    s[t] = v;
    __syncthreads();
    for (int off = 1; off < NBUF; off <<= 1) {
        int u = (t >= off) ? s[t - off] : 0;
        __syncthreads();
        s[t] += u;
        __syncthreads();
    }
    if (t < NB) {
        int base = s[t] - v;   // exclusive
        bucketBase[t] = base;
        gCursor[t] = base;
    }
    if (t == 0) bucketBase[NB] = E;
}

// Scatter edges into bucket-contiguous packed array.
__global__ void __launch_bounds__(256)
bucket_scatter(const int* __restrict__ row, const int* __restrict__ col,
               int* __restrict__ gCursor, int* __restrict__ packed, int E, int NB) {
    __shared__ int hist[NBUF];
    __shared__ int base[NBUF];
    int t = threadIdx.x;
    int blockBase = blockIdx.x * EPB;
    for (int i = t; i < NB; i += 256) hist[i] = 0;
    __syncthreads();
    for (int i = t; i < EPB; i += 256) {           // pass 1: histogram
        int e = blockBase + i;
        if (e < E) atomicAdd(&hist[col[e] >> BSH], 1);
    }
    __syncthreads();
    for (int b = t; b < NB; b += 256) {            // claim global ranges
        int c = hist[b];
        base[b] = c ? atomicAdd(&gCursor[b], c) : 0;
        hist[b] = 0;
    }
    __syncthreads();
    for (int i = t; i < EPB; i += 256) {           // pass 2: rank + write
        int e = blockBase + i;
        if (e < E) {
            int c = col[e];
            int b = c >> BSH;
            int r = atomicAdd(&hist[b], 1);
            packed[base[b] + r] = (row[e] << BSH) | (c & (BN - 1));
        }
    }
}

// Per bucket: degree hist -> rowPtr + dinv (pair-scan over 512 with 256 thr),
// counting-sort -> srcs[] in CSR order, and prescale xs = dinv .* x.
__global__ void __launch_bounds__(256)
bucket_finalize(const int* __restrict__ packed, const int* __restrict__ bucketBase,
                int* __restrict__ rowPtr, float* __restrict__ dinv,
                int* __restrict__ srcs, const float4* __restrict__ x4,
                float4* __restrict__ xs4, int N, int E) {
    __shared__ int cnt[BN];
    __shared__ int ps[256];
    __shared__ int cur[BN];
    __shared__ float sdv[BN];
    int bkt = blockIdx.x;
    int t = threadIdx.x;
    int nodeBase = bkt << BSH;
    cnt[t] = 0;
    cnt[t + 256] = 0;
    __syncthreads();
    int beg = bucketBase[bkt], end = bucketBase[bkt + 1];
    for (int e = beg + t; e < end; e += 256)
        atomicAdd(&cnt[packed[e] & (BN - 1)], 1);
    __syncthreads();
    int v0 = cnt[2 * t], v1 = cnt[2 * t + 1];
    int s = v0 + v1;
    ps[t] = s;
    __syncthreads();
    for (int off = 1; off < 256; off <<= 1) {      // inclusive scan of pair sums
        int u = (t >= off) ? ps[t - off] : 0;
        __syncthreads();
        ps[t] += u;
        __syncthreads();
    }
    int p0 = beg + ps[t] - s;                      // exclusive prefix
    int p1 = p0 + v0;
    cur[2 * t] = p0;
    cur[2 * t + 1] = p1;
    float d0 = rsqrtf((float)v0 + 1.0f);
    float d1 = rsqrtf((float)v1 + 1.0f);
    sdv[2 * t] = d0;
    sdv[2 * t + 1] = d1;
    int n0 = nodeBase + 2 * t, n1 = n0 + 1;
    if (n0 < N) { rowPtr[n0] = p0; dinv[n0] = d0; }
    if (n1 < N) { rowPtr[n1] = p1; dinv[n1] = d1; }
    if (bkt == 0 && t == 0) rowPtr[N] = E;
    __syncthreads();
    for (int e = beg + t; e < end; e += 256) {     // counting sort (2nd read: L2)
        int w = packed[e];
        int pos = atomicAdd(&cur[w & (BN - 1)], 1);
        srcs[pos] = w >> BSH;
    }
    // prescale: xs = dinv .* x (4 float4 per node row)
    for (int i = t; i < BN * 4; i += 256) {
        int n = i >> 2;
        int g = nodeBase + n;
        if (g < N) {
            float4 v = x4[(size_t)g * 4 + (i & 3)];
            float d = sdv[n];
            v.x *= d; v.y *= d; v.z *= d; v.w *= d;
            xs4[(size_t)g * 4 + (i & 3)] = v;
        }
    }
}

// Layer 1: gather xs (16 ch), fused W1 GEMM + bias + ReLU; writes hs1=dinv.*h1.
// 4 lanes per node (float4 each); block = 64 nodes.
__global__ void __launch_bounds__(256)
gather_conv1(const int* __restrict__ rowPtr, const int* __restrict__ srcs,
             const float* __restrict__ xs, const float* __restrict__ dinv,
             const float* __restrict__ W1, const float* __restrict__ b1,
             float* __restrict__ hs1, int N) {
    __shared__ float A[64][17];
    __shared__ float sW[16 * 32];
    __shared__ float sb[32];
    int t = threadIdx.x;
    for (int i = t; i < 512; i += 256) sW[i] = W1[i];
    if (t < 32) sb[t] = b1[t];
    int tt = blockIdx.x * 256 + t;
    int node = tt >> 2, q = tt & 3, ln = t >> 2;
    float ax = 0.f, ay = 0.f, az = 0.f, aw = 0.f;
    float di = 0.f;
    if (node < N) {
        int beg = rowPtr[node], end = rowPtr[node + 1];
        for (int e = beg; e < end; ++e) {
            int s = srcs[e];
            const float4 v = *(const float4*)(xs + (size_t)s * 16 + q * 4);
            ax += v.x; ay += v.y; az += v.z; aw += v.w;
        }
        const float4 sv = *(const float4*)(xs + (size_t)node * 16 + q * 4);
        ax += sv.x; ay += sv.y; az += sv.z; aw += sv.w;
        di = dinv[node];
        ax *= di; ay *= di; az *= di; aw *= di;
    }
    A[ln][q * 4 + 0] = ax;
    A[ln][q * 4 + 1] = ay;
    A[ln][q * 4 + 2] = az;
    A[ln][q * 4 + 3] = aw;
    __syncthreads();
    if (node < N) {
        int k0 = q * 8;
        float acc[8];
#pragma unroll
        for (int j = 0; j < 8; ++j) acc[j] = sb[k0 + j];
#pragma unroll
        for (int c = 0; c < 16; ++c) {
            float ac = A[ln][c];
#pragma unroll
            for (int j = 0; j < 8; ++j) acc[j] += ac * sW[c * 32 + k0 + j];
        }
        float4 r0, r1;
        r0.x = di * fmaxf(acc[0], 0.f);
        r0.y = di * fmaxf(acc[1], 0.f);
        r0.z = di * fmaxf(acc[2], 0.f);
        r0.w = di * fmaxf(acc[3], 0.f);
        r1.x = di * fmaxf(acc[4], 0.f);
        r1.y = di * fmaxf(acc[5], 0.f);
        r1.z = di * fmaxf(acc[6], 0.f);
        r1.w = di * fmaxf(acc[7], 0.f);
        *(float4*)(hs1 + (size_t)node * 32 + k0) = r0;
        *(float4*)(hs1 + (size_t)node * 32 + k0 + 4) = r1;
    }
}

// Layer 2 + head: gather hs1 (32 ch), fused W2+b2+ReLU, Wl1+bl1+ReLU, Wl4+bl4.
// 8 lanes per node (float4 each); block = 32 nodes. Writes out[N].
__global__ void __launch_bounds__(256)
gather_conv2_head(const int* __restrict__ rowPtr, const int* __restrict__ srcs,
                  const float* __restrict__ hs1, const float* __restrict__ dinv,
                  const float* __restrict__ W2, const float* __restrict__ b2,
                  const float* __restrict__ Wl1, const float* __restrict__ bl1,
                  const float* __restrict__ Wl4, const float* __restrict__ bl4,
                  float* __restrict__ out, int N) {
    __shared__ float A[32][33];
    __shared__ float sW2[1024];
    __shared__ float sWl1[1024];
    __shared__ float sb2[32], sbl1[32], sWl4[32];
    __shared__ float sbl4;
    int t = threadIdx.x;
    for (int i = t; i < 1024; i += 256) { sW2[i] = W2[i]; sWl1[i] = Wl1[i]; }
    if (t < 32) { sb2[t] = b2[t]; sbl1[t] = bl1[t]; sWl4[t] = Wl4[t]; }
    if (t == 0) sbl4 = bl4[0];
    int tt = blockIdx.x * 256 + t;
    int node = tt >> 3, q = tt & 7, ln = t >> 3;
    float ax = 0.f, ay = 0.f, az = 0.f, aw = 0.f;
    if (node < N) {
        int beg = rowPtr[node], end = rowPtr[node + 1];
        for (int e = beg; e < end; ++e) {
            int s = srcs[e];
            const float4 v = *(const float4*)(hs1 + (size_t)s * 32 + q * 4);
            ax += v.x; ay += v.y; az += v.z; aw += v.w;
        }
        const float4 sv = *(const float4*)(hs1 + (size_t)node * 32 + q * 4);
        ax += sv.x; ay += sv.y; az += sv.z; aw += sv.w;
        float di = dinv[node];
        ax *= di; ay *= di; az *= di; aw *= di;
    }
    A[ln][q * 4 + 0] = ax;
    A[ln][q * 4 + 1] = ay;
    A[ln][q * 4 + 2] = az;
    A[ln][q * 4 + 3] = aw;
    __syncthreads();
    int k0 = q * 4;
    float h2[4];
#pragma unroll
    for (int j = 0; j < 4; ++j) h2[j] = sb2[k0 + j];
#pragma unroll
    for (int c = 0; c < 32; ++c) {
        float ac = A[ln][c];
#pragma unroll
        for (int j = 0; j < 4; ++j) h2[j] += ac * sW2[c * 32 + k0 + j];
    }
#pragma unroll
    for (int j = 0; j < 4; ++j) h2[j] = fmaxf(h2[j], 0.f);
    __syncthreads();
#pragma unroll
    for (int j = 0; j < 4; ++j) A[ln][k0 + j] = h2[j];
    __syncthreads();
    float h3[4];
#pragma unroll
    for (int j = 0; j < 4; ++j) h3[j] = sbl1[k0 + j];
#pragma unroll
    for (int c = 0; c < 32; ++c) {
        float ac = A[ln][c];
#pragma unroll
        for (int j = 0; j < 4; ++j) h3[j] += ac * sWl1[c * 32 + k0 + j];
    }
    float p = 0.f;
#pragma unroll
    for (int j = 0; j < 4; ++j) p += fmaxf(h3[j], 0.f) * sWl4[k0 + j];
    p += __shfl_xor(p, 1);
    p += __shfl_xor(p, 2);
    p += __shfl_xor(p, 4);
    if (q == 0 && node < N) out[node] = p + sbl4;
}

extern "C" void kernel_launch(void* const* d_in, const int* in_sizes, int n_in,
                              void* d_out, int out_size, void* d_ws, size_t ws_size,
                              hipStream_t stream) {
    const float* x   = (const float*)d_in[0];
    const int*   ei  = (const int*)d_in[1];
    const float* W1  = (const float*)d_in[2];
    const float* b1  = (const float*)d_in[3];
    const float* W2  = (const float*)d_in[4];
    const float* b2  = (const float*)d_in[5];
    const float* Wl1 = (const float*)d_in[6];
    const float* bl1 = (const float*)d_in[7];
    const float* Wl4 = (const float*)d_in[8];
    const float* bl4 = (const float*)d_in[9];
    float* out = (float*)d_out;

    const int N = in_sizes[0] / 16;
    const int E = in_sizes[1] / 2;
    const int* row = ei;        // edge_index[0] : source j
    const int* col = ei + E;    // edge_index[1] : target i
    const int NB = (N + BN - 1) >> BSH;

    // workspace layout (512B aligned)
    char* ws = (char*)d_ws;
    auto align = [](size_t v) { return (v + 511) & ~(size_t)511; };
    size_t o = 0;
    int*   bt         = (int*)(ws + o);   o = align(o + (size_t)NBUF * 4);
    int*   bucketBase = (int*)(ws + o);   o = align(o + (size_t)(NBUF + 1) * 4);
    int*   gCursor    = (int*)(ws + o);   o = align(o + (size_t)NBUF * 4);
    int*   rowPtr     = (int*)(ws + o);   o = align(o + (size_t)(N + 1) * 4);
    float* dinv       = (float*)(ws + o); o = align(o + (size_t)N * 4);
    int*   packed     = (int*)(ws + o);   o = align(o + (size_t)E * 4);
    int*   srcs       = (int*)(ws + o);   o = align(o + (size_t)E * 4);
    float* xs         = (float*)(ws + o); o = align(o + (size_t)N * 16 * 4);
    float* hs1        = (float*)(ws + o); o = align(o + (size_t)N * 32 * 4);

    const int BLK = 256;
    int gridSc = (E + EPB - 1) / EPB;
    int gridG1 = (N * 4 + BLK - 1) / BLK;
    int gridG2 = (N * 8 + BLK - 1) / BLK;

    // --- bucket layout + edge reorder + degrees + prescale ---
    hipMemsetAsync(bt, 0, (size_t)NBUF * 4, stream);
    bucket_hist<<<gridSc, BLK, 0, stream>>>(col, bt, E, NB);
    scan_init<<<1, NBUF, 0, stream>>>(bt, bucketBase, gCursor, NB, E);
    bucket_scatter<<<gridSc, BLK, 0, stream>>>(row, col, gCursor, packed, E, NB);
    bucket_finalize<<<NB, BLK, 0, stream>>>(packed, bucketBase, rowPtr, dinv, srcs,
                                            (const float4*)x, (float4*)xs, N, E);

    // --- conv1 (gather xs + fused W1) ---
    gather_conv1<<<gridG1, BLK, 0, stream>>>(rowPtr, srcs, xs, dinv, W1, b1, hs1, N);

    // --- conv2 + MLP head, fully fused ---
    gather_conv2_head<<<gridG2, BLK, 0, stream>>>(rowPtr, srcs, hs1, dinv,
                                                  W2, b2, Wl1, bl1, Wl4, bl4, out, N);
}

// Round 8
// 297.443 us; speedup vs baseline: 5.6317x; 1.0733x over previous
//
#include <hip/hip_runtime.h>
#include <hip/hip_fp16.h>
#include <math.h>

// ---------------------------------------------------------------------------
// GCN forward, fully fused, fp16 feature tables (fp32 accumulate).
//   xs  = fp16( dinv .* x )              [N,16] half, 32B/row
//   A1[i] = dinv[i]*(sum xs[src] + xs[i]);  h1 = relu(A1@W1+b1)
//   hs1 = fp16( dinv .* h1 )             [N,32] half, 64B/row
//   A2[i] = dinv[i]*(sum hs1[src] + hs1[i]); h2 = relu(A2@W2+b2)
//   out = relu(h2@Wl1+bl1) @ Wl4 + bl4
// Pipeline: bucket_hist -> scan_init -> bucket_scatter -> bucket_finalize
//   (rowPtr+dinv+counting sort+prescale) -> gather_conv1 -> gather_conv2_head
// ---------------------------------------------------------------------------

#define BN 512           // nodes per bucket
#define BSH 9            // log2(BN)
#define NBUF 256         // max buckets (N <= 131072)
#define EPB 8192         // edges per scatter block

// Per-block LDS histogram over buckets, flush to global bt[].
__global__ void __launch_bounds__(256)
bucket_hist(const int* __restrict__ col, int* __restrict__ bt, int E, int NB) {
    __shared__ int hist[NBUF];
    int t = threadIdx.x;
    int blockBase = blockIdx.x * EPB;
    for (int i = t; i < NB; i += 256) hist[i] = 0;
    __syncthreads();
    for (int i = t; i < EPB; i += 256) {
        int e = blockBase + i;
        if (e < E) atomicAdd(&hist[col[e] >> BSH], 1);
    }
    __syncthreads();
    for (int b = t; b < NB; b += 256) {
        int c = hist[b];
        if (c) atomicAdd(&bt[b], c);
    }
}

// Single-block exclusive scan over NB (<=256) bucket totals.
__global__ void scan_init(const int* __restrict__ bt, int* __restrict__ bucketBase,
                          int* __restrict__ gCursor, int NB, int E) {
    __shared__ int s[NBUF];
    int t = threadIdx.x;
    int v = (t < NB) ? bt[t] : 0;
    s[t] = v;
    __syncthreads();
    for (int off = 1; off < NBUF; off <<= 1) {
        int u = (t >= off) ? s[t - off] : 0;
        __syncthreads();
        s[t] += u;
        __syncthreads();
    }
    if (t < NB) {
        int base = s[t] - v;   // exclusive
        bucketBase[t] = base;
        gCursor[t] = base;
    }
    if (t == 0) bucketBase[NB] = E;
}

// Scatter edges into bucket-contiguous packed array.
__global__ void __launch_bounds__(256)
bucket_scatter(const int* __restrict__ row, const int* __restrict__ col,
               int* __restrict__ gCursor, int* __restrict__ packed, int E, int NB) {
    __shared__ int hist[NBUF];
    __shared__ int base[NBUF];
    int t = threadIdx.x;
    int blockBase = blockIdx.x * EPB;
    for (int i = t; i < NB; i += 256) hist[i] = 0;
    __syncthreads();
    for (int i = t; i < EPB; i += 256) {           // pass 1: histogram
        int e = blockBase + i;
        if (e < E) atomicAdd(&hist[col[e] >> BSH], 1);
    }
    __syncthreads();
    for (int b = t; b < NB; b += 256) {            // claim global ranges
        int c = hist[b];
        base[b] = c ? atomicAdd(&gCursor[b], c) : 0;
        hist[b] = 0;
    }
    __syncthreads();
    for (int i = t; i < EPB; i += 256) {           // pass 2: rank + write
        int e = blockBase + i;
        if (e < E) {
            int c = col[e];
            int b = c >> BSH;
            int r = atomicAdd(&hist[b], 1);
            packed[base[b] + r] = (row[e] << BSH) | (c & (BN - 1));
        }
    }
}

// Per bucket: degree hist -> rowPtr + dinv, counting-sort -> srcs[],
// prescale xs = fp16(dinv .* x).
__global__ void __launch_bounds__(256)
bucket_finalize(const int* __restrict__ packed, const int* __restrict__ bucketBase,
                int* __restrict__ rowPtr, float* __restrict__ dinv,
                int* __restrict__ srcs, const float4* __restrict__ x4,
                __half* __restrict__ xs, int N, int E) {
    __shared__ int cnt[BN];
    __shared__ int ps[256];
    __shared__ int cur[BN];
    __shared__ float sdv[BN];
    int bkt = blockIdx.x;
    int t = threadIdx.x;
    int nodeBase = bkt << BSH;
    cnt[t] = 0;
    cnt[t + 256] = 0;
    __syncthreads();
    int beg = bucketBase[bkt], end = bucketBase[bkt + 1];
    for (int e = beg + t; e < end; e += 256)
        atomicAdd(&cnt[packed[e] & (BN - 1)], 1);
    __syncthreads();
    int v0 = cnt[2 * t], v1 = cnt[2 * t + 1];
    int s = v0 + v1;
    ps[t] = s;
    __syncthreads();
    for (int off = 1; off < 256; off <<= 1) {      // inclusive scan of pair sums
        int u = (t >= off) ? ps[t - off] : 0;
        __syncthreads();
        ps[t] += u;
        __syncthreads();
    }
    int p0 = beg + ps[t] - s;                      // exclusive prefix
    int p1 = p0 + v0;
    cur[2 * t] = p0;
    cur[2 * t + 1] = p1;
    float d0 = rsqrtf((float)v0 + 1.0f);
    float d1 = rsqrtf((float)v1 + 1.0f);
    sdv[2 * t] = d0;
    sdv[2 * t + 1] = d1;
    int n0 = nodeBase + 2 * t, n1 = n0 + 1;
    if (n0 < N) { rowPtr[n0] = p0; dinv[n0] = d0; }
    if (n1 < N) { rowPtr[n1] = p1; dinv[n1] = d1; }
    if (bkt == 0 && t == 0) rowPtr[N] = E;
    __syncthreads();
    for (int e = beg + t; e < end; e += 256) {     // counting sort (2nd read: L2)
        int w = packed[e];
        int pos = atomicAdd(&cur[w & (BN - 1)], 1);
        srcs[pos] = w >> BSH;
    }
    // prescale: xs = fp16(dinv .* x); 2 threads/node, 16B (8 halves) each
    for (int i = t; i < BN * 2; i += 256) {
        int n = i >> 1, hf = i & 1;
        int g = nodeBase + n;
        if (g < N) {
            float d = sdv[n];
            float4 va = x4[(size_t)g * 4 + hf * 2];
            float4 vb = x4[(size_t)g * 4 + hf * 2 + 1];
            __half2 h0 = __floats2half2_rn(va.x * d, va.y * d);
            __half2 h1 = __floats2half2_rn(va.z * d, va.w * d);
            __half2 h2 = __floats2half2_rn(vb.x * d, vb.y * d);
            __half2 h3 = __floats2half2_rn(vb.z * d, vb.w * d);
            uint4 u;
            u.x = *(unsigned*)&h0; u.y = *(unsigned*)&h1;
            u.z = *(unsigned*)&h2; u.w = *(unsigned*)&h3;
            *(uint4*)(xs + (size_t)g * 16 + hf * 8) = u;
        }
    }
}

// Layer 1: gather xs (16ch half), fused W1 GEMM + bias + ReLU; hs1=fp16(dinv.*h1).
// 2 lanes per node, 16B (8 halves) each; block = 128 nodes.
__global__ void __launch_bounds__(256)
gather_conv1(const int* __restrict__ rowPtr, const int* __restrict__ srcs,
             const __half* __restrict__ xs, const float* __restrict__ dinv,
             const float* __restrict__ W1, const float* __restrict__ b1,
             __half* __restrict__ hs1, int N) {
    __shared__ float A[128][17];
    __shared__ float sW[16 * 32];
    __shared__ float sb[32];
    int t = threadIdx.x;
    for (int i = t; i < 512; i += 256) sW[i] = W1[i];
    if (t < 32) sb[t] = b1[t];
    int tt = blockIdx.x * 256 + t;
    int node = tt >> 1, q = tt & 1, ln = t >> 1;
    float a[8] = {0.f, 0.f, 0.f, 0.f, 0.f, 0.f, 0.f, 0.f};
    float di = 0.f;
    if (node < N) {
        int beg = rowPtr[node], end = rowPtr[node + 1];
        for (int e = beg; e < end; ++e) {
            int s = srcs[e];
            const uint4 u = *(const uint4*)(xs + (size_t)s * 16 + q * 8);
            float2 f;
            f = __half22float2(*(const __half2*)&u.x); a[0] += f.x; a[1] += f.y;
            f = __half22float2(*(const __half2*)&u.y); a[2] += f.x; a[3] += f.y;
            f = __half22float2(*(const __half2*)&u.z); a[4] += f.x; a[5] += f.y;
            f = __half22float2(*(const __half2*)&u.w); a[6] += f.x; a[7] += f.y;
        }
        const uint4 u = *(const uint4*)(xs + (size_t)node * 16 + q * 8);
        float2 f;
        f = __half22float2(*(const __half2*)&u.x); a[0] += f.x; a[1] += f.y;
        f = __half22float2(*(const __half2*)&u.y); a[2] += f.x; a[3] += f.y;
        f = __half22float2(*(const __half2*)&u.z); a[4] += f.x; a[5] += f.y;
        f = __half22float2(*(const __half2*)&u.w); a[6] += f.x; a[7] += f.y;
        di = dinv[node];
#pragma unroll
        for (int j = 0; j < 8; ++j) a[j] *= di;
    }
#pragma unroll
    for (int j = 0; j < 8; ++j) A[ln][q * 8 + j] = a[j];
    __syncthreads();
    if (node < N) {
        int k0 = q * 16;
        float acc[16];
#pragma unroll
        for (int j = 0; j < 16; ++j) acc[j] = sb[k0 + j];
#pragma unroll
        for (int c = 0; c < 16; ++c) {
            float ac = A[ln][c];
#pragma unroll
            for (int j = 0; j < 16; ++j) acc[j] += ac * sW[c * 32 + k0 + j];
        }
        __half2 h[8];
#pragma unroll
        for (int j = 0; j < 8; ++j)
            h[j] = __floats2half2_rn(di * fmaxf(acc[2 * j], 0.f),
                                     di * fmaxf(acc[2 * j + 1], 0.f));
        uint4 u0, u1;
        u0.x = *(unsigned*)&h[0]; u0.y = *(unsigned*)&h[1];
        u0.z = *(unsigned*)&h[2]; u0.w = *(unsigned*)&h[3];
        u1.x = *(unsigned*)&h[4]; u1.y = *(unsigned*)&h[5];
        u1.z = *(unsigned*)&h[6]; u1.w = *(unsigned*)&h[7];
        *(uint4*)(hs1 + (size_t)node * 32 + k0) = u0;
        *(uint4*)(hs1 + (size_t)node * 32 + k0 + 8) = u1;
    }
}

// Layer 2 + head: gather hs1 (32ch half), fused W2+b2+ReLU, Wl1+bl1+ReLU, Wl4+bl4.
// 4 lanes per node, 16B (8 halves) each; block = 64 nodes. Writes out[N].
__global__ void __launch_bounds__(256)
gather_conv2_head(const int* __restrict__ rowPtr, const int* __restrict__ srcs,
                  const __half* __restrict__ hs1, const float* __restrict__ dinv,
                  const float* __restrict__ W2, const float* __restrict__ b2,
                  const float* __restrict__ Wl1, const float* __restrict__ bl1,
                  const float* __restrict__ Wl4, const float* __restrict__ bl4,
                  float* __restrict__ out, int N) {
    __shared__ float A[64][33];
    __shared__ float sW2[1024];
    __shared__ float sWl1[1024];
    __shared__ float sb2[32], sbl1[32], sWl4[32];
    __shared__ float sbl4;
    int t = threadIdx.x;
    for (int i = t; i < 1024; i += 256) { sW2[i] = W2[i]; sWl1[i] = Wl1[i]; }
    if (t < 32) { sb2[t] = b2[t]; sbl1[t] = bl1[t]; sWl4[t] = Wl4[t]; }
    if (t == 0) sbl4 = bl4[0];
    int tt = blockIdx.x * 256 + t;
    int node = tt >> 2, q = tt & 3, ln = t >> 2;
    float a[8] = {0.f, 0.f, 0.f, 0.f, 0.f, 0.f, 0.f, 0.f};
    if (node < N) {
        int beg = rowPtr[node], end = rowPtr[node + 1];
        for (int e = beg; e < end; ++e) {
            int s = srcs[e];
            const uint4 u = *(const uint4*)(hs1 + (size_t)s * 32 + q * 8);
            float2 f;
            f = __half22float2(*(const __half2*)&u.x); a[0] += f.x; a[1] += f.y;
            f = __half22float2(*(const __half2*)&u.y); a[2] += f.x; a[3] += f.y;
            f = __half22float2(*(const __half2*)&u.z); a[4] += f.x; a[5] += f.y;
            f = __half22float2(*(const __half2*)&u.w); a[6] += f.x; a[7] += f.y;
        }
        const uint4 u = *(const uint4*)(hs1 + (size_t)node * 32 + q * 8);
        float2 f;
        f = __half22float2(*(const __half2*)&u.x); a[0] += f.x; a[1] += f.y;
        f = __half22float2(*(const __half2*)&u.y); a[2] += f.x; a[3] += f.y;
        f = __half22float2(*(const __half2*)&u.z); a[4] += f.x; a[5] += f.y;
        f = __half22float2(*(const __half2*)&u.w); a[6] += f.x; a[7] += f.y;
        float di = dinv[node];
#pragma unroll
        for (int j = 0; j < 8; ++j) a[j] *= di;
    }
#pragma unroll
    for (int j = 0; j < 8; ++j) A[ln][q * 8 + j] = a[j];
    __syncthreads();
    int k0 = q * 8;
    float h2[8];
#pragma unroll
    for (int j = 0; j < 8; ++j) h2[j] = sb2[k0 + j];
#pragma unroll
    for (int c = 0; c < 32; ++c) {
        float ac = A[ln][c];
#pragma unroll
        for (int j = 0; j < 8; ++j) h2[j] += ac * sW2[c * 32 + k0 + j];
    }
#pragma unroll
    for (int j = 0; j < 8; ++j) h2[j] = fmaxf(h2[j], 0.f);
    __syncthreads();
#pragma unroll
    for (int j = 0; j < 8; ++j) A[ln][k0 + j] = h2[j];
    __syncthreads();
    float h3[8];
#pragma unroll
    for (int j = 0; j < 8; ++j) h3[j] = sbl1[k0 + j];
#pragma unroll
    for (int c = 0; c < 32; ++c) {
        float ac = A[ln][c];
#pragma unroll
        for (int j = 0; j < 8; ++j) h3[j] += ac * sWl1[c * 32 + k0 + j];
    }
    float p = 0.f;
#pragma unroll
    for (int j = 0; j < 8; ++j) p += fmaxf(h3[j], 0.f) * sWl4[k0 + j];
    p += __shfl_xor(p, 1);
    p += __shfl_xor(p, 2);
    if (q == 0 && node < N) out[node] = p + sbl4;
}

extern "C" void kernel_launch(void* const* d_in, const int* in_sizes, int n_in,
                              void* d_out, int out_size, void* d_ws, size_t ws_size,
                              hipStream_t stream) {
    const float* x   = (const float*)d_in[0];
    const int*   ei  = (const int*)d_in[1];
    const float* W1  = (const float*)d_in[2];
    const float* b1  = (const float*)d_in[3];
    const float* W2  = (const float*)d_in[4];
    const float* b2  = (const float*)d_in[5];
    const float* Wl1 = (const float*)d_in[6];
    const float* bl1 = (const float*)d_in[7];
    const float* Wl4 = (const float*)d_in[8];
    const float* bl4 = (const float*)d_in[9];
    float* out = (float*)d_out;

    const int N = in_sizes[0] / 16;
    const int E = in_sizes[1] / 2;
    const int* row = ei;        // edge_index[0] : source j
    const int* col = ei + E;    // edge_index[1] : target i
    const int NB = (N + BN - 1) >> BSH;

    // workspace layout (512B aligned)
    char* ws = (char*)d_ws;
    auto align = [](size_t v) { return (v + 511) & ~(size_t)511; };
    size_t o = 0;
    int*    bt         = (int*)(ws + o);    o = align(o + (size_t)NBUF * 4);
    int*    bucketBase = (int*)(ws + o);    o = align(o + (size_t)(NBUF + 1) * 4);
    int*    gCursor    = (int*)(ws + o);    o = align(o + (size_t)NBUF * 4);
    int*    rowPtr     = (int*)(ws + o);    o = align(o + (size_t)(N + 1) * 4);
    float*  dinv       = (float*)(ws + o);  o = align(o + (size_t)N * 4);
    int*    packed     = (int*)(ws + o);    o = align(o + (size_t)E * 4);
    int*    srcs       = (int*)(ws + o);    o = align(o + (size_t)E * 4);
    __half* xs         = (__half*)(ws + o); o = align(o + (size_t)N * 16 * 2);
    __half* hs1        = (__half*)(ws + o); o = align(o + (size_t)N * 32 * 2);

    const int BLK = 256;
    int gridSc = (E + EPB - 1) / EPB;
    int gridG1 = (N * 2 + BLK - 1) / BLK;
    int gridG2 = (N * 4 + BLK - 1) / BLK;

    // --- bucket layout + edge reorder + degrees + prescale ---
    hipMemsetAsync(bt, 0, (size_t)NBUF * 4, stream);
    bucket_hist<<<gridSc, BLK, 0, stream>>>(col, bt, E, NB);
    scan_init<<<1, NBUF, 0, stream>>>(bt, bucketBase, gCursor, NB, E);
    bucket_scatter<<<gridSc, BLK, 0, stream>>>(row, col, gCursor, packed, E, NB);
    bucket_finalize<<<NB, BLK, 0, stream>>>(packed, bucketBase, rowPtr, dinv, srcs,
                                            (const float4*)x, xs, N, E);

    // --- conv1 (gather xs + fused W1) ---
    gather_conv1<<<gridG1, BLK, 0, stream>>>(rowPtr, srcs, xs, dinv, W1, b1, hs1, N);

    // --- conv2 + MLP head, fully fused ---
    gather_conv2_head<<<gridG2, BLK, 0, stream>>>(rowPtr, srcs, hs1, dinv,
                                                  W2, b2, Wl1, bl1, Wl4, bl4, out, N);
}